// Round 1
// baseline (2551.432 us; speedup 1.0000x reference)
//
#include <hip/hip_runtime.h>
#include <hip/hip_bf16.h>
#include <stdint.h>

// ---------------------------------------------------------------------------
// SwiGLU with int8 weight-quant emulation (VNNILinear), MI355X gfx950.
// Plan: quantize->dequant weights to bf16 (matches reference int8 round-trip),
// cast x to bf16, then two MFMA GEMMs:
//   kernel A (fused): h = silu(x@w1^T) * (x@w3^T)   [8192 x 8192]
//   kernel B:         out = h @ w2^T                [8192 x 4096] fp32
// GEMM structure = m97 128^2 tile, BK=32, global_load_lds(16B), 4 waves.
// ---------------------------------------------------------------------------

typedef short bf16x8 __attribute__((ext_vector_type(8)));
typedef float f32x4 __attribute__((ext_vector_type(4)));

__device__ __forceinline__ unsigned short f2bf(float f) {
  unsigned u = __builtin_bit_cast(unsigned, f);
  u += 0x7FFFu + ((u >> 16) & 1u);   // RNE; inputs are finite/normal
  return (unsigned short)(u >> 16);
}

#define GLOAD_LDS16(gaddr, laddr)                                             \
  __builtin_amdgcn_global_load_lds(                                           \
      (const __attribute__((address_space(1))) void*)(gaddr),                 \
      (__attribute__((address_space(3))) void*)(laddr), 16, 0, 0)

// --------------------------- preprocessing --------------------------------

// Per-row symmetric int8 quant round-trip, output bf16. One block per row.
__global__ void quant_rows_kernel(const float* __restrict__ w,
                                  unsigned short* __restrict__ wq, int cols) {
  const int row = blockIdx.x;
  const float* wr = w + (size_t)row * cols;
  unsigned short* wqr = wq + (size_t)row * cols;

  float m = 0.f;
  for (int c = threadIdx.x * 4; c < cols; c += blockDim.x * 4) {
    float4 v = *reinterpret_cast<const float4*>(wr + c);
    m = fmaxf(m, fmaxf(fmaxf(fabsf(v.x), fabsf(v.y)),
                       fmaxf(fabsf(v.z), fabsf(v.w))));
  }
#pragma unroll
  for (int off = 32; off; off >>= 1) m = fmaxf(m, __shfl_xor(m, off));
  __shared__ float smax[4];
  if ((threadIdx.x & 63) == 0) smax[threadIdx.x >> 6] = m;
  __syncthreads();
  m = fmaxf(fmaxf(smax[0], smax[1]), fmaxf(smax[2], smax[3]));

  const float scale = fmaxf(m, 1e-6f) / 127.0f;  // matches clip(max,1e-6)/127
  for (int c = threadIdx.x * 4; c < cols; c += blockDim.x * 4) {
    float4 v = *reinterpret_cast<const float4*>(wr + c);
    ushort4 o;
    o.x = f2bf(rintf(v.x / scale) * scale);   // rintf == round-half-even
    o.y = f2bf(rintf(v.y / scale) * scale);
    o.z = f2bf(rintf(v.z / scale) * scale);
    o.w = f2bf(rintf(v.w / scale) * scale);
    *reinterpret_cast<ushort4*>(wqr + c) = o;
  }
}

__global__ void cast_bf16_kernel(const float* __restrict__ x,
                                 unsigned short* __restrict__ xb, int n) {
  for (int i = (blockIdx.x * blockDim.x + threadIdx.x) * 4; i < n;
       i += gridDim.x * blockDim.x * 4) {
    float4 v = *reinterpret_cast<const float4*>(x + i);
    ushort4 o;
    o.x = f2bf(v.x); o.y = f2bf(v.y); o.z = f2bf(v.z); o.w = f2bf(v.w);
    *reinterpret_cast<ushort4*>(xb + i) = o;
  }
}

// ------------------------------ GEMMs -------------------------------------
// Both operands row-major [rows][K] bf16 (B is the transposed weight), so the
// A- and B-fragment LDS reads have identical form.
// Tile 128x128, BK=32, 4 waves in 2x2, 4x4 16x16x32 fragments per wave.

__device__ __forceinline__ void xcd_swizzle(int& bx, int& by, int gx, int gy) {
  // bijective when (gx*gy) % 8 == 0 (true for both grids here)
  int nwg = gx * gy;
  int bid = by * gx + bx;
  int cpx = nwg >> 3;
  int s = (bid & 7) * cpx + (bid >> 3);
  by = s / gx;
  bx = s % gx;
}

__global__ __launch_bounds__(256, 2)
void gemm_swiglu_kernel(const unsigned short* __restrict__ A,   // [M][K] x
                        const unsigned short* __restrict__ B1,  // [N][K] w1
                        const unsigned short* __restrict__ B3,  // [N][K] w3
                        unsigned short* __restrict__ H,         // [M][N] bf16
                        int M, int N, int K) {
  __shared__ alignas(16) unsigned short sA[128 * 32];
  __shared__ alignas(16) unsigned short sB1[128 * 32];
  __shared__ alignas(16) unsigned short sB3[128 * 32];

  int bx = blockIdx.x, by = blockIdx.y;
  xcd_swizzle(bx, by, gridDim.x, gridDim.y);
  const int brow = by * 128;
  const int bcol = bx * 128;

  const int t = threadIdx.x;
  const int lane = t & 63;
  const int w = t >> 6;
  const int wr = w >> 1, wc = w & 1;

  f32x4 acc1[4][4] = {};
  f32x4 acc3[4][4] = {};

  const int r0 = t >> 2;           // staging row within 64-row group
  const int ch = (t & 3) * 8;      // staging col (elements)

  const unsigned short* gA  = A  + (size_t)brow * K;
  const unsigned short* gB1 = B1 + (size_t)bcol * K;
  const unsigned short* gB3 = B3 + (size_t)bcol * K;

  const int arow = wr * 64 + (lane & 15);   // A-frag base row in tile
  const int bcolf = wc * 64 + (lane & 15);  // B-frag base row in tile
  const int kh = (lane >> 4) * 8;           // k-offset within BK=32

  for (int k0 = 0; k0 < K; k0 += 32) {
    GLOAD_LDS16(gA  + (size_t)(r0)      * K + k0 + ch, sA  + t * 8);
    GLOAD_LDS16(gA  + (size_t)(r0 + 64) * K + k0 + ch, sA  + 2048 + t * 8);
    GLOAD_LDS16(gB1 + (size_t)(r0)      * K + k0 + ch, sB1 + t * 8);
    GLOAD_LDS16(gB1 + (size_t)(r0 + 64) * K + k0 + ch, sB1 + 2048 + t * 8);
    GLOAD_LDS16(gB3 + (size_t)(r0)      * K + k0 + ch, sB3 + t * 8);
    GLOAD_LDS16(gB3 + (size_t)(r0 + 64) * K + k0 + ch, sB3 + 2048 + t * 8);
    __syncthreads();

    bf16x8 af[4], b1f[4], b3f[4];
#pragma unroll
    for (int m = 0; m < 4; ++m)
      af[m] = *reinterpret_cast<const bf16x8*>(&sA[(arow + m * 16) * 32 + kh]);
#pragma unroll
    for (int n = 0; n < 4; ++n) {
      b1f[n] = *reinterpret_cast<const bf16x8*>(&sB1[(bcolf + n * 16) * 32 + kh]);
      b3f[n] = *reinterpret_cast<const bf16x8*>(&sB3[(bcolf + n * 16) * 32 + kh]);
    }
#pragma unroll
    for (int m = 0; m < 4; ++m)
#pragma unroll
      for (int n = 0; n < 4; ++n) {
        acc1[m][n] = __builtin_amdgcn_mfma_f32_16x16x32_bf16(af[m], b1f[n],
                                                             acc1[m][n], 0, 0, 0);
        acc3[m][n] = __builtin_amdgcn_mfma_f32_16x16x32_bf16(af[m], b3f[n],
                                                             acc3[m][n], 0, 0, 0);
      }
    __syncthreads();
  }

  // epilogue: h = silu(y1) * y3 -> bf16
  const int orow = brow + wr * 64 + (lane >> 4) * 4;
  const int ocol = bcol + wc * 64 + (lane & 15);
#pragma unroll
  for (int m = 0; m < 4; ++m)
#pragma unroll
    for (int n = 0; n < 4; ++n)
#pragma unroll
      for (int r = 0; r < 4; ++r) {
        float y1 = acc1[m][n][r];
        float y3 = acc3[m][n][r];
        float hv = (y1 / (1.f + __expf(-y1))) * y3;
        H[(size_t)(orow + m * 16 + r) * N + (ocol + n * 16)] = f2bf(hv);
      }
}

__global__ __launch_bounds__(256, 2)
void gemm_bt_kernel(const unsigned short* __restrict__ A,  // [M][K] h
                    const unsigned short* __restrict__ B,  // [N][K] w2
                    float* __restrict__ C,                 // [M][N] fp32
                    int M, int N, int K) {
  __shared__ alignas(16) unsigned short sA[128 * 32];
  __shared__ alignas(16) unsigned short sB[128 * 32];

  int bx = blockIdx.x, by = blockIdx.y;
  xcd_swizzle(bx, by, gridDim.x, gridDim.y);
  const int brow = by * 128;
  const int bcol = bx * 128;

  const int t = threadIdx.x;
  const int lane = t & 63;
  const int w = t >> 6;
  const int wr = w >> 1, wc = w & 1;

  f32x4 acc[4][4] = {};

  const int r0 = t >> 2;
  const int ch = (t & 3) * 8;

  const unsigned short* gA = A + (size_t)brow * K;
  const unsigned short* gB = B + (size_t)bcol * K;

  const int arow = wr * 64 + (lane & 15);
  const int bcolf = wc * 64 + (lane & 15);
  const int kh = (lane >> 4) * 8;

  for (int k0 = 0; k0 < K; k0 += 32) {
    GLOAD_LDS16(gA + (size_t)(r0)      * K + k0 + ch, sA + t * 8);
    GLOAD_LDS16(gA + (size_t)(r0 + 64) * K + k0 + ch, sA + 2048 + t * 8);
    GLOAD_LDS16(gB + (size_t)(r0)      * K + k0 + ch, sB + t * 8);
    GLOAD_LDS16(gB + (size_t)(r0 + 64) * K + k0 + ch, sB + 2048 + t * 8);
    __syncthreads();

    bf16x8 af[4], bf[4];
#pragma unroll
    for (int m = 0; m < 4; ++m)
      af[m] = *reinterpret_cast<const bf16x8*>(&sA[(arow + m * 16) * 32 + kh]);
#pragma unroll
    for (int n = 0; n < 4; ++n)
      bf[n] = *reinterpret_cast<const bf16x8*>(&sB[(bcolf + n * 16) * 32 + kh]);
#pragma unroll
    for (int m = 0; m < 4; ++m)
#pragma unroll
      for (int n = 0; n < 4; ++n)
        acc[m][n] = __builtin_amdgcn_mfma_f32_16x16x32_bf16(af[m], bf[n],
                                                            acc[m][n], 0, 0, 0);
    __syncthreads();
  }

  const int orow = brow + wr * 64 + (lane >> 4) * 4;
  const int ocol = bcol + wc * 64 + (lane & 15);
#pragma unroll
  for (int m = 0; m < 4; ++m)
#pragma unroll
    for (int n = 0; n < 4; ++n)
#pragma unroll
      for (int r = 0; r < 4; ++r)
        C[(size_t)(orow + m * 16 + r) * N + (ocol + n * 16)] = acc[m][n][r];
}

// ------------------------------ launch -------------------------------------

extern "C" void kernel_launch(void* const* d_in, const int* in_sizes, int n_in,
                              void* d_out, int out_size, void* d_ws,
                              size_t ws_size, hipStream_t stream) {
  const float* x  = (const float*)d_in[0];
  const float* w1 = (const float*)d_in[1];
  const float* w2 = (const float*)d_in[2];
  const float* w3 = (const float*)d_in[3];
  float* out = (float*)d_out;

  const int DIM = 4096, HID = 8192;
  const int M = in_sizes[0] / DIM;  // 8192 (= 4*2048)

  // workspace layout (bf16 as ushort): 384 MiB total
  unsigned short* xb  = (unsigned short*)d_ws;     // M*DIM
  unsigned short* w1b = xb  + (size_t)M * DIM;     // HID*DIM
  unsigned short* w3b = w1b + (size_t)HID * DIM;   // HID*DIM
  unsigned short* w2b = w3b + (size_t)HID * DIM;   // DIM*HID
  unsigned short* h   = w2b + (size_t)DIM * HID;   // M*HID

  quant_rows_kernel<<<HID, 256, 0, stream>>>(w1, w1b, DIM);
  quant_rows_kernel<<<HID, 256, 0, stream>>>(w3, w3b, DIM);
  quant_rows_kernel<<<DIM, 256, 0, stream>>>(w2, w2b, HID);
  cast_bf16_kernel<<<2048, 256, 0, stream>>>(x, xb, M * DIM);

  gemm_swiglu_kernel<<<dim3(HID / 128, M / 128), 256, 0, stream>>>(
      xb, w1b, w3b, h, M, HID, DIM);
  gemm_bt_kernel<<<dim3(DIM / 128, M / 128), 256, 0, stream>>>(
      h, w2b, out, M, DIM, HID);
}

// Round 2
// 1742.570 us; speedup vs baseline: 1.4642x; 1.4642x over previous
//
#include <hip/hip_runtime.h>
#include <hip/hip_bf16.h>
#include <stdint.h>

// ---------------------------------------------------------------------------
// SwiGLU + int8 weight-quant emulation (VNNILinear), MI355X gfx950.
// Round 2: 8-phase deep-pipelined GEMMs (T2 swizzle + T3/T4 counted vmcnt +
// T5 setprio). 4-slot LDS ring, BK=32, stage 2 K-tiles ahead, vmcnt(4) gate
// once per K-tile, never drained in steady state.
//   kernel A (fused, 256x128 tile, dual-B): h = silu(x@w1^T) * (x@w3^T)
//   kernel B (256x256 tile):                out = h @ w2^T  (fp32)
// ---------------------------------------------------------------------------

typedef short bf16x8 __attribute__((ext_vector_type(8)));
typedef float f32x4 __attribute__((ext_vector_type(4)));

__device__ __forceinline__ unsigned short f2bf(float f) {
  unsigned u = __builtin_bit_cast(unsigned, f);
  u += 0x7FFFu + ((u >> 16) & 1u);   // RNE; inputs finite/normal
  return (unsigned short)(u >> 16);
}

#define GLOAD_LDS16(gaddr, laddr)                                             \
  __builtin_amdgcn_global_load_lds(                                           \
      (const __attribute__((address_space(1))) void*)(gaddr),                 \
      (__attribute__((address_space(3))) void*)(laddr), 16, 0, 0)

#define FENCE()      asm volatile("" ::: "memory")
#define BAR()        __builtin_amdgcn_s_barrier()
#define WAIT_LGKM0() asm volatile("s_waitcnt lgkmcnt(0)" ::: "memory")
#define WAIT_VM4()   asm volatile("s_waitcnt vmcnt(4)" ::: "memory")
#define WAIT_VM0()   asm volatile("s_waitcnt vmcnt(0)" ::: "memory")
#define SFENCE()     __builtin_amdgcn_sched_barrier(0)

// --------------------------- preprocessing --------------------------------

__global__ void quant_rows_kernel(const float* __restrict__ w,
                                  unsigned short* __restrict__ wq, int cols) {
  const int row = blockIdx.x;
  const float* wr = w + (size_t)row * cols;
  unsigned short* wqr = wq + (size_t)row * cols;

  float m = 0.f;
  for (int c = threadIdx.x * 4; c < cols; c += blockDim.x * 4) {
    float4 v = *reinterpret_cast<const float4*>(wr + c);
    m = fmaxf(m, fmaxf(fmaxf(fabsf(v.x), fabsf(v.y)),
                       fmaxf(fabsf(v.z), fabsf(v.w))));
  }
#pragma unroll
  for (int off = 32; off; off >>= 1) m = fmaxf(m, __shfl_xor(m, off));
  __shared__ float smax[4];
  if ((threadIdx.x & 63) == 0) smax[threadIdx.x >> 6] = m;
  __syncthreads();
  m = fmaxf(fmaxf(smax[0], smax[1]), fmaxf(smax[2], smax[3]));

  const float scale = fmaxf(m, 1e-6f) / 127.0f;
  for (int c = threadIdx.x * 4; c < cols; c += blockDim.x * 4) {
    float4 v = *reinterpret_cast<const float4*>(wr + c);
    ushort4 o;
    o.x = f2bf(rintf(v.x / scale) * scale);
    o.y = f2bf(rintf(v.y / scale) * scale);
    o.z = f2bf(rintf(v.z / scale) * scale);
    o.w = f2bf(rintf(v.w / scale) * scale);
    *reinterpret_cast<ushort4*>(wqr + c) = o;
  }
}

__global__ void cast_bf16_kernel(const float* __restrict__ x,
                                 unsigned short* __restrict__ xb, int n) {
  for (int i = (blockIdx.x * blockDim.x + threadIdx.x) * 4; i < n;
       i += gridDim.x * blockDim.x * 4) {
    float4 v = *reinterpret_cast<const float4*>(x + i);
    ushort4 o;
    o.x = f2bf(v.x); o.y = f2bf(v.y); o.z = f2bf(v.z); o.w = f2bf(v.w);
    *reinterpret_cast<ushort4*>(xb + i) = o;
  }
}

// ------------------------------ GEMMs -------------------------------------

__device__ __forceinline__ void xcd_swizzle(int& bx, int& by, int gx, int gy) {
  int nwg = gx * gy;              // both grids are % 8 == 0
  int bid = by * gx + bx;
  int cpx = nwg >> 3;
  int s = (bid & 7) * cpx + (bid >> 3);
  by = s / gx;
  bx = s % gx;
}

// Swizzled fragment read: LDS row r (64 B), stored chunk = kh ^ ((r>>1)&3).
// Staging wrote global chunk gc into stored chunk sc = gc ^ ((r>>1)&3), so
// this returns global k = kh*8 .. kh*8+7.  Same involution both sides.
__device__ __forceinline__ bf16x8 frag_ld(const unsigned short* base, int r,
                                          int kh) {
  int c = kh ^ ((r >> 1) & 3);
  return *reinterpret_cast<const bf16x8*>(base + r * 32 + c * 8);
}

// FUSED: A[256][K] x, B1/B3[N][K] w1/w3, out H bf16 [M][N], BN=128.
// !FUSED: A[256][K] h, B1[N][K] w2, out C fp32 [M][N], BN=256.
template <bool FUSED>
__global__ __launch_bounds__(512, 2)
void gemm8_kernel(const unsigned short* __restrict__ A,
                  const unsigned short* __restrict__ B1,
                  const unsigned short* __restrict__ B3,
                  unsigned short* __restrict__ Hout,
                  float* __restrict__ Cout,
                  int M, int N, int K) {
  constexpr int BN = FUSED ? 128 : 256;
  constexpr int WC = FUSED ? 32 : 64;
  // 4-slot ring, 32 KB/slot: sA 256x32 (8192 sh), then B-region 8192 sh
  // (plain: B 256x32; fused: B1 128x32 @ +8192, B3 128x32 @ +12288).
  __shared__ alignas(1024) unsigned short lds[65536];  // 128 KiB

  int bx = blockIdx.x, by = blockIdx.y;
  xcd_swizzle(bx, by, gridDim.x, gridDim.y);
  const int brow = by * 256, bcol = bx * BN;

  const int t = threadIdx.x, lane = t & 63, w = t >> 6;
  const int wr = w >> 2, wc = w & 3;
  const int l15 = lane & 15, kh = lane >> 4;
  const int NT = K >> 5;

  const unsigned short* gA = A + (size_t)brow * K;
  const unsigned short* gB1 = B1 + (size_t)bcol * K;

  // staging: thread t covers LDS chunks idx = j*512+t -> (r = idx>>2, sc = idx&3)
  // source chunk gc = sc ^ ((r>>1)&3)  (same for j=0 and j=1: r jumps by 128)
  const int rS = t >> 2;
  const int gcS = (t & 3) ^ ((t >> 3) & 3);
  const unsigned short* srcA = gA + (size_t)rS * K + gcS * 8;
  const unsigned short* srcB1g = gB1 + (size_t)rS * K + gcS * 8;
  const unsigned short* srcBx =
      FUSED ? (B3 + (size_t)bcol * K + (size_t)rS * K + gcS * 8)
            : (srcB1g + (size_t)128 * K);
  const int dA0 = t * 8, dA1 = 4096 + t * 8;
  const int dB0 = 8192 + t * 8, dB1 = 12288 + t * 8;

#define STAGE_A(kt2)                                                          \
  {                                                                           \
    const int s2 = ((kt2) & 3) * 16384;                                       \
    const size_t ko = (size_t)(kt2) * 32;                                     \
    GLOAD_LDS16(srcA + ko, &lds[s2 + dA0]);                                   \
    GLOAD_LDS16(srcA + (size_t)128 * K + ko, &lds[s2 + dA1]);                 \
  }
#define STAGE_B(kt2)                                                          \
  {                                                                           \
    const int s2 = ((kt2) & 3) * 16384;                                       \
    const size_t ko = (size_t)(kt2) * 32;                                     \
    GLOAD_LDS16(srcB1g + ko, &lds[s2 + dB0]);                                 \
    GLOAD_LDS16(srcBx + ko, &lds[s2 + dB1]);                                  \
  }

  // prologue: tiles 0 and 1 in flight (8 loads); gate tile 0 (4 newest left)
  STAGE_A(0); STAGE_B(0);
  STAGE_A(1); STAGE_B(1);
  WAIT_VM4();
  FENCE(); BAR();

  f32x4 acc[8][4] = {};
  bf16x8 afr[4], bfr[4];
  const int arow0 = wr * 128 + l15;
  const int brow0 = wc * WC + l15;

  for (int k = 0; k < NT; ++k) {
    const int sl = (k & 3) * 16384;
    const unsigned short* sAp = &lds[sl];
    const unsigned short* sB1p = &lds[sl + 8192];
    const unsigned short* sB3p = &lds[sl + 12288];
    const bool pf = (k + 2 < NT);

    // ---- phase A: quadrant m0..3 x all n ----
#pragma unroll
    for (int m = 0; m < 4; ++m) afr[m] = frag_ld(sAp, arow0 + m * 16, kh);
    if (FUSED) {
      bfr[0] = frag_ld(sB1p, brow0, kh);
      bfr[1] = frag_ld(sB1p, brow0 + 16, kh);
      bfr[2] = frag_ld(sB3p, brow0, kh);
      bfr[3] = frag_ld(sB3p, brow0 + 16, kh);
    } else {
#pragma unroll
      for (int n = 0; n < 4; ++n)
        bfr[n] = frag_ld(sB1p, brow0 + n * 16, kh);
    }
    if (pf) STAGE_A(k + 2);
    FENCE(); BAR();
    WAIT_LGKM0(); SFENCE();
    __builtin_amdgcn_s_setprio(1);
#pragma unroll
    for (int m = 0; m < 4; ++m)
#pragma unroll
      for (int n = 0; n < 4; ++n)
        acc[m][n] = __builtin_amdgcn_mfma_f32_16x16x32_bf16(afr[m], bfr[n],
                                                            acc[m][n], 0, 0, 0);
    __builtin_amdgcn_s_setprio(0);
    FENCE(); BAR();

    // ---- phase B: quadrant m4..7 x all n (B frags reused) ----
#pragma unroll
    for (int m = 0; m < 4; ++m)
      afr[m] = frag_ld(sAp, arow0 + 64 + m * 16, kh);
    if (pf) {
      STAGE_B(k + 2);
      WAIT_VM4();   // gate: tile k+1 fully landed; tile k+2 (4 loads) in flight
    } else {
      WAIT_VM0();   // tail drain (last 2 iterations only)
    }
    FENCE(); BAR();
    WAIT_LGKM0(); SFENCE();
    __builtin_amdgcn_s_setprio(1);
#pragma unroll
    for (int m = 0; m < 4; ++m)
#pragma unroll
      for (int n = 0; n < 4; ++n)
        acc[m + 4][n] = __builtin_amdgcn_mfma_f32_16x16x32_bf16(
            afr[m], bfr[n], acc[m + 4][n], 0, 0, 0);
    __builtin_amdgcn_s_setprio(0);
    FENCE(); BAR();
  }
#undef STAGE_A
#undef STAGE_B

  // ---- epilogue ----
  const int orow = brow + wr * 128 + kh * 4;
  const int ocol = bcol + wc * WC + l15;
  if (FUSED) {
#pragma unroll
    for (int m = 0; m < 8; ++m)
#pragma unroll
      for (int n = 0; n < 2; ++n)
#pragma unroll
        for (int r = 0; r < 4; ++r) {
          float y1 = acc[m][n][r];
          float y3 = acc[m][n + 2][r];
          float hv = (y1 / (1.f + __expf(-y1))) * y3;
          Hout[(size_t)(orow + m * 16 + r) * N + (ocol + n * 16)] = f2bf(hv);
        }
  } else {
#pragma unroll
    for (int m = 0; m < 8; ++m)
#pragma unroll
      for (int n = 0; n < 4; ++n)
#pragma unroll
        for (int r = 0; r < 4; ++r)
          Cout[(size_t)(orow + m * 16 + r) * N + (ocol + n * 16)] =
              acc[m][n][r];
  }
}

// ------------------------------ launch -------------------------------------

extern "C" void kernel_launch(void* const* d_in, const int* in_sizes, int n_in,
                              void* d_out, int out_size, void* d_ws,
                              size_t ws_size, hipStream_t stream) {
  const float* x  = (const float*)d_in[0];
  const float* w1 = (const float*)d_in[1];
  const float* w2 = (const float*)d_in[2];
  const float* w3 = (const float*)d_in[3];
  float* out = (float*)d_out;

  const int DIM = 4096, HID = 8192;
  const int M = in_sizes[0] / DIM;  // 8192

  unsigned short* xb  = (unsigned short*)d_ws;     // M*DIM
  unsigned short* w1b = xb  + (size_t)M * DIM;     // HID*DIM
  unsigned short* w3b = w1b + (size_t)HID * DIM;   // HID*DIM
  unsigned short* w2b = w3b + (size_t)HID * DIM;   // DIM*HID
  unsigned short* h   = w2b + (size_t)DIM * HID;   // M*HID

  quant_rows_kernel<<<HID, 256, 0, stream>>>(w1, w1b, DIM);
  quant_rows_kernel<<<HID, 256, 0, stream>>>(w3, w3b, DIM);
  quant_rows_kernel<<<DIM, 256, 0, stream>>>(w2, w2b, HID);
  cast_bf16_kernel<<<2048, 256, 0, stream>>>(x, xb, M * DIM);

  gemm8_kernel<true><<<dim3(HID / 128, M / 256), 512, 0, stream>>>(
      xb, w1b, w3b, h, nullptr, M, HID, DIM);
  gemm8_kernel<false><<<dim3(DIM / 256, M / 256), 512, 0, stream>>>(
      h, w2b, nullptr, nullptr, out, M, DIM, HID);
}

// Round 3
// 1252.998 us; speedup vs baseline: 2.0363x; 1.3907x over previous
//
#include <hip/hip_runtime.h>
#include <hip/hip_bf16.h>
#include <stdint.h>

// ---------------------------------------------------------------------------
// SwiGLU + int8 weight-quant emulation (VNNILinear), MI355X gfx950. Round 3:
//   GEMM1/3 (fused): int8 MFMA 16x16x64 (w_q bit-exact vs reference round,
//     x per-row int8), BK=64, 4-slot LDS ring, stage 3 tiles ahead, vmcnt(8).
//   GEMM2: bf16 MFMA 16x16x32, BK=32, same deep pipeline.
// ---------------------------------------------------------------------------

typedef short bf16x8 __attribute__((ext_vector_type(8)));
typedef float f32x4 __attribute__((ext_vector_type(4)));
typedef int   i32x4 __attribute__((ext_vector_type(4)));

__device__ __forceinline__ unsigned short f2bf(float f) {
  unsigned u = __builtin_bit_cast(unsigned, f);
  u += 0x7FFFu + ((u >> 16) & 1u);   // RNE
  return (unsigned short)(u >> 16);
}

#define GLOAD_LDS16(gaddr, laddr)                                             \
  __builtin_amdgcn_global_load_lds(                                           \
      (const __attribute__((address_space(1))) void*)(gaddr),                 \
      (__attribute__((address_space(3))) void*)(laddr), 16, 0, 0)

#define FENCE()      asm volatile("" ::: "memory")
#define BAR()        __builtin_amdgcn_s_barrier()
#define WAIT_LGKM0() asm volatile("s_waitcnt lgkmcnt(0)" ::: "memory")
#define WAIT_VM8()   asm volatile("s_waitcnt vmcnt(8)" ::: "memory")
#define WAIT_VM4()   asm volatile("s_waitcnt vmcnt(4)" ::: "memory")
#define WAIT_VM0()   asm volatile("s_waitcnt vmcnt(0)" ::: "memory")
#define SFENCE()     __builtin_amdgcn_sched_barrier(0)

// --------------------------- preprocessing --------------------------------

// Per-row int8 quant: q[row][col], scale[row] = max(|row|, clip)/127.
// rintf(w/s) in f32 == jnp.round(w/scale) bit-exactly (both RNE).
__global__ void quant_rows_i8_kernel(const float* __restrict__ w,
                                     char* __restrict__ q,
                                     float* __restrict__ scale, int cols,
                                     float clip) {
  const int row = blockIdx.x;
  const float* wr = w + (size_t)row * cols;
  char* qr = q + (size_t)row * cols;

  float m = 0.f;
  for (int c = threadIdx.x * 4; c < cols; c += blockDim.x * 4) {
    float4 v = *reinterpret_cast<const float4*>(wr + c);
    m = fmaxf(m, fmaxf(fmaxf(fabsf(v.x), fabsf(v.y)),
                       fmaxf(fabsf(v.z), fabsf(v.w))));
  }
#pragma unroll
  for (int off = 32; off; off >>= 1) m = fmaxf(m, __shfl_xor(m, off));
  __shared__ float smax[4];
  if ((threadIdx.x & 63) == 0) smax[threadIdx.x >> 6] = m;
  __syncthreads();
  m = fmaxf(fmaxf(smax[0], smax[1]), fmaxf(smax[2], smax[3]));

  const float s = fmaxf(m, clip) / 127.0f;
  if (threadIdx.x == 0) scale[row] = s;
  for (int c = threadIdx.x * 4; c < cols; c += blockDim.x * 4) {
    float4 v = *reinterpret_cast<const float4*>(wr + c);
    int b0 = (int)rintf(v.x / s), b1 = (int)rintf(v.y / s);
    int b2 = (int)rintf(v.z / s), b3 = (int)rintf(v.w / s);
    unsigned pk = (b0 & 0xff) | ((b1 & 0xff) << 8) | ((b2 & 0xff) << 16)
                  | ((b3 & 0xff) << 24);
    *reinterpret_cast<unsigned*>(qr + c) = pk;
  }
}

// Per-row bf16 int8-roundtrip quant (for w2, consumed by the bf16 GEMM).
__global__ void quant_rows_bf16_kernel(const float* __restrict__ w,
                                       unsigned short* __restrict__ wq,
                                       int cols) {
  const int row = blockIdx.x;
  const float* wr = w + (size_t)row * cols;
  unsigned short* wqr = wq + (size_t)row * cols;

  float m = 0.f;
  for (int c = threadIdx.x * 4; c < cols; c += blockDim.x * 4) {
    float4 v = *reinterpret_cast<const float4*>(wr + c);
    m = fmaxf(m, fmaxf(fmaxf(fabsf(v.x), fabsf(v.y)),
                       fmaxf(fabsf(v.z), fabsf(v.w))));
  }
#pragma unroll
  for (int off = 32; off; off >>= 1) m = fmaxf(m, __shfl_xor(m, off));
  __shared__ float smax[4];
  if ((threadIdx.x & 63) == 0) smax[threadIdx.x >> 6] = m;
  __syncthreads();
  m = fmaxf(fmaxf(smax[0], smax[1]), fmaxf(smax[2], smax[3]));

  const float s = fmaxf(m, 1e-6f) / 127.0f;
  for (int c = threadIdx.x * 4; c < cols; c += blockDim.x * 4) {
    float4 v = *reinterpret_cast<const float4*>(wr + c);
    ushort4 o;
    o.x = f2bf(rintf(v.x / s) * s);
    o.y = f2bf(rintf(v.y / s) * s);
    o.z = f2bf(rintf(v.z / s) * s);
    o.w = f2bf(rintf(v.w / s) * s);
    *reinterpret_cast<ushort4*>(wqr + c) = o;
  }
}

// ------------------------------ GEMMs -------------------------------------

__device__ __forceinline__ void xcd_swizzle(int& bx, int& by, int gx, int gy) {
  int nwg = gx * gy;              // both grids are % 8 == 0
  int bid = by * gx + bx;
  int cpx = nwg >> 3;
  int s = (bid & 7) * cpx + (bid >> 3);
  by = s / gx;
  bx = s % gx;
}

// int8 tile: rows of 64 B (K=64 i8), 4 chunks of 16 B, chunk-XOR swizzle.
__device__ __forceinline__ i32x4 frag_ld_i8(const char* base, int r, int kh) {
  int c = kh ^ ((r >> 1) & 3);
  return *reinterpret_cast<const i32x4*>(base + r * 64 + c * 16);
}

// bf16 tile: rows of 32 sh (64 B), chunks of 8 sh.
__device__ __forceinline__ bf16x8 frag_ld_bf(const unsigned short* base, int r,
                                             int kh) {
  int c = kh ^ ((r >> 1) & 3);
  return *reinterpret_cast<const bf16x8*>(base + r * 32 + c * 8);
}

// Fused int8 GEMM: H = silu((xq@w1q^T)*sx*sw1) * ((xq@w3q^T)*sx*sw3), bf16.
// Tile 256x128(H), BK=64, 8 waves 2x4, per-wave 128 rows x 32 dual-cols.
__global__ __launch_bounds__(512, 2)
void gemm_i8_swiglu_kernel(const char* __restrict__ Aq,
                           const char* __restrict__ B1q,
                           const char* __restrict__ B3q,
                           const float* __restrict__ sx,
                           const float* __restrict__ sw1,
                           const float* __restrict__ sw3,
                           unsigned short* __restrict__ H,
                           int M, int N, int K) {
  // 4 slots x 32 KB: A 256x64 (16 KB), B1 128x64 (8 KB), B3 128x64 (8 KB)
  __shared__ alignas(1024) char lds[131072];

  int bx = blockIdx.x, by = blockIdx.y;
  xcd_swizzle(bx, by, gridDim.x, gridDim.y);
  const int brow = by * 256, bcol = bx * 128;

  const int t = threadIdx.x, lane = t & 63, w = t >> 6;
  const int wr = w >> 2, wc = w & 3;
  const int l15 = lane & 15, kh = lane >> 4;
  const int NT = K >> 6;   // BK=64

  const char* gA = Aq + (size_t)brow * K;
  // staging: thread t -> row rS=t>>2, stored chunk sc=t&3, src chunk gc
  const int rS = t >> 2;
  const int gcS = (t & 3) ^ ((t >> 3) & 3);
  const char* srcA = gA + (size_t)rS * K + gcS * 16;
  const char* srcB1 = B1q + (size_t)bcol * K + (size_t)rS * K + gcS * 16;
  const char* srcB3 = B3q + (size_t)bcol * K + (size_t)rS * K + gcS * 16;

#define STAGE_A(kt)                                                           \
  {                                                                           \
    const int s2 = ((kt) & 3) * 32768;                                        \
    const size_t ko = (size_t)(kt) * 64;                                      \
    GLOAD_LDS16(srcA + ko, lds + s2 + t * 16);                                \
    GLOAD_LDS16(srcA + (size_t)128 * K + ko, lds + s2 + 8192 + t * 16);       \
  }
#define STAGE_B(kt)                                                           \
  {                                                                           \
    const int s2 = ((kt) & 3) * 32768;                                        \
    const size_t ko = (size_t)(kt) * 64;                                      \
    GLOAD_LDS16(srcB1 + ko, lds + s2 + 16384 + t * 16);                       \
    GLOAD_LDS16(srcB3 + ko, lds + s2 + 24576 + t * 16);                       \
  }

  // prologue: tiles 0,1,2 in flight (12 loads); drain to 8 -> tile 0 landed
  STAGE_A(0); STAGE_B(0);
  STAGE_A(1); STAGE_B(1);
  STAGE_A(2); STAGE_B(2);
  WAIT_VM8();
  FENCE(); BAR();

  i32x4 acc[8][4] = {};          // n: 0,1 = w1 cols; 2,3 = w3 cols
  i32x4 afr[4], bfr[4];
  const int arow0 = wr * 128 + l15;
  const int brow0 = wc * 32 + l15;

  for (int k = 0; k < NT; ++k) {
    const char* sAp = lds + (k & 3) * 32768;
    const char* sB1p = sAp + 16384;
    const char* sB3p = sAp + 24576;
    const bool pf = (k + 3 < NT);

    // ---- phase A: rows m0..3 ----
#pragma unroll
    for (int m = 0; m < 4; ++m) afr[m] = frag_ld_i8(sAp, arow0 + m * 16, kh);
    bfr[0] = frag_ld_i8(sB1p, brow0, kh);
    bfr[1] = frag_ld_i8(sB1p, brow0 + 16, kh);
    bfr[2] = frag_ld_i8(sB3p, brow0, kh);
    bfr[3] = frag_ld_i8(sB3p, brow0 + 16, kh);
    if (pf) STAGE_A(k + 3);
    FENCE(); BAR();
    WAIT_LGKM0(); SFENCE();
    __builtin_amdgcn_s_setprio(1);
#pragma unroll
    for (int m = 0; m < 4; ++m)
#pragma unroll
      for (int n = 0; n < 4; ++n)
        acc[m][n] = __builtin_amdgcn_mfma_i32_16x16x64_i8(afr[m], bfr[n],
                                                          acc[m][n], 0, 0, 0);
    __builtin_amdgcn_s_setprio(0);
    FENCE(); BAR();

    // ---- phase B: rows m4..7 (B frags reused) ----
#pragma unroll
    for (int m = 0; m < 4; ++m)
      afr[m] = frag_ld_i8(sAp, arow0 + 64 + m * 16, kh);
    if (pf) {
      STAGE_B(k + 3);
      WAIT_VM8();      // tile k+1 fully landed; k+2,k+3 in flight
    } else if (k == NT - 3) {
      WAIT_VM4();
    } else {
      WAIT_VM0();
    }
    FENCE(); BAR();
    WAIT_LGKM0(); SFENCE();
    __builtin_amdgcn_s_setprio(1);
#pragma unroll
    for (int m = 0; m < 4; ++m)
#pragma unroll
      for (int n = 0; n < 4; ++n)
        acc[m + 4][n] = __builtin_amdgcn_mfma_i32_16x16x64_i8(
            afr[m], bfr[n], acc[m + 4][n], 0, 0, 0);
    __builtin_amdgcn_s_setprio(0);
    FENCE(); BAR();
  }
#undef STAGE_A
#undef STAGE_B

  // ---- epilogue: dequant + SwiGLU -> bf16 ----
  const int orow = brow + wr * 128 + kh * 4;
  const int ocol = bcol + wc * 32 + l15;
  const float sw1a = sw1[ocol], sw1b = sw1[ocol + 16];
  const float sw3a = sw3[ocol], sw3b = sw3[ocol + 16];
#pragma unroll
  for (int m = 0; m < 8; ++m)
#pragma unroll
    for (int r = 0; r < 4; ++r) {
      const int row = orow + m * 16 + r;
      const float sxr = sx[row];
      float y1a = (float)acc[m][0][r] * (sxr * sw1a);
      float y1b = (float)acc[m][1][r] * (sxr * sw1b);
      float y3a = (float)acc[m][2][r] * (sxr * sw3a);
      float y3b = (float)acc[m][3][r] * (sxr * sw3b);
      float ha = (y1a / (1.f + __expf(-y1a))) * y3a;
      float hb = (y1b / (1.f + __expf(-y1b))) * y3b;
      H[(size_t)row * N + ocol] = f2bf(ha);
      H[(size_t)row * N + ocol + 16] = f2bf(hb);
    }
}

// bf16 GEMM: C = A @ B^T (fp32 out). Tile 256x256, BK=32, deep pipeline.
__global__ __launch_bounds__(512, 2)
void gemm_bf16_kernel(const unsigned short* __restrict__ A,
                      const unsigned short* __restrict__ B,
                      float* __restrict__ C, int M, int N, int K) {
  // 4 slots x 32 KB: A 256x32 (16 KB) + B 256x32 (16 KB)
  __shared__ alignas(1024) unsigned short lds[65536];

  int bx = blockIdx.x, by = blockIdx.y;
  xcd_swizzle(bx, by, gridDim.x, gridDim.y);
  const int brow = by * 256, bcol = bx * 256;

  const int t = threadIdx.x, lane = t & 63, w = t >> 6;
  const int wr = w >> 2, wc = w & 3;
  const int l15 = lane & 15, kh = lane >> 4;
  const int NT = K >> 5;

  const int rS = t >> 2;
  const int gcS = (t & 3) ^ ((t >> 3) & 3);
  const unsigned short* srcA = A + (size_t)brow * K + (size_t)rS * K + gcS * 8;
  const unsigned short* srcB = B + (size_t)bcol * K + (size_t)rS * K + gcS * 8;

#define STAGE_A(kt)                                                           \
  {                                                                           \
    const int s2 = ((kt) & 3) * 16384;                                        \
    const size_t ko = (size_t)(kt) * 32;                                      \
    GLOAD_LDS16(srcA + ko, &lds[s2 + t * 8]);                                 \
    GLOAD_LDS16(srcA + (size_t)128 * K + ko, &lds[s2 + 4096 + t * 8]);        \
  }
#define STAGE_B(kt)                                                           \
  {                                                                           \
    const int s2 = ((kt) & 3) * 16384;                                        \
    const size_t ko = (size_t)(kt) * 32;                                      \
    GLOAD_LDS16(srcB + ko, &lds[s2 + 8192 + t * 8]);                          \
    GLOAD_LDS16(srcB + (size_t)128 * K + ko, &lds[s2 + 12288 + t * 8]);       \
  }

  STAGE_A(0); STAGE_B(0);
  STAGE_A(1); STAGE_B(1);
  STAGE_A(2); STAGE_B(2);
  WAIT_VM8();
  FENCE(); BAR();

  f32x4 acc[8][4] = {};
  bf16x8 afr[4], bfr[4];
  const int arow0 = wr * 128 + l15;
  const int brow0 = wc * 64 + l15;

  for (int k = 0; k < NT; ++k) {
    const unsigned short* sAp = &lds[(k & 3) * 16384];
    const unsigned short* sBp = sAp + 8192;
    const bool pf = (k + 3 < NT);

    // ---- phase A ----
#pragma unroll
    for (int m = 0; m < 4; ++m) afr[m] = frag_ld_bf(sAp, arow0 + m * 16, kh);
#pragma unroll
    for (int n = 0; n < 4; ++n) bfr[n] = frag_ld_bf(sBp, brow0 + n * 16, kh);
    if (pf) STAGE_A(k + 3);
    FENCE(); BAR();
    WAIT_LGKM0(); SFENCE();
    __builtin_amdgcn_s_setprio(1);
#pragma unroll
    for (int m = 0; m < 4; ++m)
#pragma unroll
      for (int n = 0; n < 4; ++n)
        acc[m][n] = __builtin_amdgcn_mfma_f32_16x16x32_bf16(afr[m], bfr[n],
                                                            acc[m][n], 0, 0, 0);
    __builtin_amdgcn_s_setprio(0);
    FENCE(); BAR();

    // ---- phase B ----
#pragma unroll
    for (int m = 0; m < 4; ++m)
      afr[m] = frag_ld_bf(sAp, arow0 + 64 + m * 16, kh);
    if (pf) {
      STAGE_B(k + 3);
      WAIT_VM8();
    } else if (k == NT - 3) {
      WAIT_VM4();
    } else {
      WAIT_VM0();
    }
    FENCE(); BAR();
    WAIT_LGKM0(); SFENCE();
    __builtin_amdgcn_s_setprio(1);
#pragma unroll
    for (int m = 0; m < 4; ++m)
#pragma unroll
      for (int n = 0; n < 4; ++n)
        acc[m + 4][n] = __builtin_amdgcn_mfma_f32_16x16x32_bf16(
            afr[m], bfr[n], acc[m + 4][n], 0, 0, 0);
    __builtin_amdgcn_s_setprio(0);
    FENCE(); BAR();
  }
#undef STAGE_A
#undef STAGE_B

  const int orow = brow + wr * 128 + kh * 4;
  const int ocol = bcol + wc * 64 + l15;
#pragma unroll
  for (int m = 0; m < 8; ++m)
#pragma unroll
    for (int n = 0; n < 4; ++n)
#pragma unroll
      for (int r = 0; r < 4; ++r)
        C[(size_t)(orow + m * 16 + r) * N + (ocol + n * 16)] = acc[m][n][r];
}

// ------------------------------ launch -------------------------------------

extern "C" void kernel_launch(void* const* d_in, const int* in_sizes, int n_in,
                              void* d_out, int out_size, void* d_ws,
                              size_t ws_size, hipStream_t stream) {
  const float* x  = (const float*)d_in[0];
  const float* w1 = (const float*)d_in[1];
  const float* w2 = (const float*)d_in[2];
  const float* w3 = (const float*)d_in[3];
  float* out = (float*)d_out;

  const int DIM = 4096, HID = 8192;
  const int M = in_sizes[0] / DIM;  // 8192

  // workspace layout
  char* xq  = (char*)d_ws;                              // M*DIM    (32 MB)
  char* w1q = xq + (size_t)M * DIM;                     // HID*DIM  (32 MB)
  char* w3q = w1q + (size_t)HID * DIM;                  // HID*DIM  (32 MB)
  unsigned short* w2b = (unsigned short*)(w3q + (size_t)HID * DIM);  // 64 MB
  unsigned short* h = w2b + (size_t)DIM * HID;          // M*HID bf16 (128 MB)
  float* sx  = (float*)(h + (size_t)M * HID);           // M
  float* sw1 = sx + M;                                  // HID
  float* sw3 = sw1 + HID;                               // HID

  quant_rows_i8_kernel<<<HID, 256, 0, stream>>>(w1, w1q, sw1, DIM, 1e-6f);
  quant_rows_i8_kernel<<<HID, 256, 0, stream>>>(w3, w3q, sw3, DIM, 1e-6f);
  quant_rows_i8_kernel<<<M, 256, 0, stream>>>(x, xq, sx, DIM, 1e-30f);
  quant_rows_bf16_kernel<<<DIM, 256, 0, stream>>>(w2, w2b, HID);

  gemm_i8_swiglu_kernel<<<dim3(HID / 128, M / 256), 512, 0, stream>>>(
      xq, w1q, w3q, sx, sw1, sw3, h, M, HID, DIM);
  gemm_bf16_kernel<<<dim3(DIM / 256, M / 256), 512, 0, stream>>>(
      h, w2b, out, M, DIM, HID);
}